// Round 12
// baseline (180.688 us; speedup 1.0000x reference)
//
#include <hip/hip_runtime.h>

// LIF neuron scan over time (dim 0).
// x: (T=8, 16, 64, 56, 56) f32.  Per spatial element, sequential over t:
//   mem   = (mem_old - spike_prev) * 0.25 + x[t]
//   spike = round(clip(mem, 0, 4))      // round-half-to-even, like jnp.round
// out[t] = spike.
//
// R1/R4/R6: 62-65us, 2.45 TB/s, pinned regardless of load clustering attempts
// (VGPR=28 -> clustering never survived; Little's law says MLP=1 suffices
// anyway). Theory: (a) one-shot 3136-block grid -> ragged 2-generation
// occupancy, ramp+tail; (b) write-allocations thrash L3 (FETCH = exactly half
// the input because the harness's d_out poison + our writes evict input).
// Fix: persistent grid-stride shape (2 chunks/thread, interleaved -> ILP=2)
// + nontemporal stores (output is write-once, skip cache allocation).
// R7: __builtin_nontemporal_store rejects HIP float4 (class type) -> use a
// clang native ext_vector_type(4) for the store. Same plan otherwise.
// R8-R11: broker timeouts, no data. Identical resubmit.

#pragma clang fp contract(off)

constexpr int   LIF_T     = 8;
constexpr float LIF_DECAY = 0.25f;

typedef float f32x4 __attribute__((ext_vector_type(4)));

__device__ __forceinline__ float lif_q4(float m)
{
    #pragma clang fp contract(off)
    return rintf(fminf(fmaxf(m, 0.f), 4.f));
}

__global__ __launch_bounds__(256) void
lif_kernel(const f32x4* __restrict__ x, f32x4* __restrict__ out,
           int n4, int half)
{
    // Separate sub/mul/add roundings (no FMA contraction) to match the
    // numpy/JAX fp32 reference bit-exactly at round() half-way points.
    #pragma clang fp contract(off)

    const int tid    = blockIdx.x * blockDim.x + threadIdx.x;
    const int stride = gridDim.x * blockDim.x;

    for (int i = tid; i < half; i += stride) {
        const int j = i + half;   // second, independent chunk -> ILP/MLP = 2

        float amx = 0.f, amy = 0.f, amz = 0.f, amw = 0.f;
        float asx = 0.f, asy = 0.f, asz = 0.f, asw = 0.f;
        float bmx = 0.f, bmy = 0.f, bmz = 0.f, bmw = 0.f;
        float bsx = 0.f, bsy = 0.f, bsz = 0.f, bsw = 0.f;

        #pragma unroll
        for (int t = 0; t < LIF_T; ++t) {
            const f32x4 av = x[t * n4 + i];
            const f32x4 bv = x[t * n4 + j];

            amx = (amx - asx) * LIF_DECAY + av.x;
            amy = (amy - asy) * LIF_DECAY + av.y;
            amz = (amz - asz) * LIF_DECAY + av.z;
            amw = (amw - asw) * LIF_DECAY + av.w;

            bmx = (bmx - bsx) * LIF_DECAY + bv.x;
            bmy = (bmy - bsy) * LIF_DECAY + bv.y;
            bmz = (bmz - bsz) * LIF_DECAY + bv.z;
            bmw = (bmw - bsw) * LIF_DECAY + bv.w;

            asx = lif_q4(amx); asy = lif_q4(amy);
            asz = lif_q4(amz); asw = lif_q4(amw);
            bsx = lif_q4(bmx); bsy = lif_q4(bmy);
            bsz = lif_q4(bmz); bsw = lif_q4(bmw);

            f32x4 ao; ao.x = asx; ao.y = asy; ao.z = asz; ao.w = asw;
            f32x4 bo; bo.x = bsx; bo.y = bsy; bo.z = bsz; bo.w = bsw;
            // Output is written once and never read by this kernel:
            // nontemporal -> don't allocate in L2/L3, don't evict the input.
            __builtin_nontemporal_store(ao, &out[t * n4 + i]);
            __builtin_nontemporal_store(bo, &out[t * n4 + j]);
        }
    }
}

// Scalar fallback for elements not covered by the paired-chunk kernel
// (n4 odd and/or n_per_t % 4 != 0). Not expected for this shape.
__global__ void
lif_kernel_tail(const float* __restrict__ x, float* __restrict__ out,
                int n_per_t, int start)
{
    #pragma clang fp contract(off)
    const int i = start + blockIdx.x * blockDim.x + threadIdx.x;
    if (i >= n_per_t) return;

    float mem = 0.f, spike = 0.f;
    #pragma unroll
    for (int t = 0; t < LIF_T; ++t) {
        mem   = (mem - spike) * LIF_DECAY + x[t * n_per_t + i];
        spike = rintf(fminf(fmaxf(mem, 0.f), 4.f));
        out[t * n_per_t + i] = spike;
    }
}

extern "C" void kernel_launch(void* const* d_in, const int* in_sizes, int n_in,
                              void* d_out, int out_size, void* d_ws, size_t ws_size,
                              hipStream_t stream)
{
    const float* x   = (const float*)d_in[0];
    float*       out = (float*)d_out;

    const int n_total = in_sizes[0];          // T * N
    const int n_per_t = n_total / LIF_T;      // spatial elements per timestep
    const int n4      = n_per_t / 4;          // float4 chunks per timestep
    const int half    = n4 / 2;               // paired-chunk count

    if (half > 0) {
        const int block = 256;
        int grid = (half + block - 1) / block;    // 1568 for this shape
        if (grid > 2048) grid = 2048;             // grid-stride beyond this
        lif_kernel<<<grid, block, 0, stream>>>(
            (const f32x4*)x, (f32x4*)out, n4, half);
    }

    const int tail_start = 2 * half * 4;          // first uncovered element
    const int tail_n     = n_per_t - tail_start;
    if (tail_n > 0) {
        const int block = 64;
        const int grid  = (tail_n + block - 1) / block;
        lif_kernel_tail<<<grid, block, 0, stream>>>(x, out, n_per_t, tail_start);
    }
}